// Round 2
// baseline (1702.832 us; speedup 1.0000x reference)
//
#include <hip/hip_runtime.h>
#include <hip/hip_bf16.h>

#define N_OBJ 8192
#define N_REL 32768
#define HID   512
#define POOL  4096
#define NOC   151
#define NRC   51

// gemm2: 256x128 tiles, 8 waves; each block walks NT n-tiles, NSPLIT blocks per m-row.
#define NSPLIT 8
#define NT    (POOL / 128 / NSPLIT)   // 4

typedef __bf16 bf16_t;
typedef __attribute__((ext_vector_type(8))) __bf16 bf16x8;
typedef __attribute__((ext_vector_type(4))) __bf16 bf16x4;
typedef __attribute__((ext_vector_type(4))) float f32x4;

// Async global->LDS, 16B per lane. LDS dest semantics: wave-uniform base + lane*16.
__device__ __forceinline__ void async_copy16(const void* g, void* l) {
    __builtin_amdgcn_global_load_lds((__attribute__((address_space(1))) void*)g,
                                     (__attribute__((address_space(3))) void*)l,
                                     16, 0, 0);
}

// ---------------- small prep kernels ----------------

__global__ void convert_bf16_kernel(const float* __restrict__ in,
                                    bf16_t* __restrict__ out, int n4) {
    int i = blockIdx.x * blockDim.x + threadIdx.x;
    int stride = gridDim.x * blockDim.x;
    for (; i < n4; i += stride) {
        float4 v = ((const float4*)in)[i];
        bf16x4 o;
        o[0] = (bf16_t)v.x; o[1] = (bf16_t)v.y; o[2] = (bf16_t)v.z; o[3] = (bf16_t)v.w;
        ((bf16x4*)out)[i] = o;
    }
}

// in: f32 [K][C] row-major -> out: bf16 [Cpad][K] (transposed, zero-padded in C)
__global__ void transpose_bf16_kernel(const float* __restrict__ in,
                                      bf16_t* __restrict__ out,
                                      int K, int C, int Cpad) {
    __shared__ float tile[32][33];
    int cb = blockIdx.x * 32, kb = blockIdx.y * 32;
    int tx = threadIdx.x, ty = threadIdx.y; // 32 x 8
    #pragma unroll
    for (int i = 0; i < 32; i += 8) {
        int k = kb + ty + i, c = cb + tx;
        float v = (k < K && c < C) ? in[(size_t)k * C + c] : 0.0f;
        tile[ty + i][tx] = v;
    }
    __syncthreads();
    #pragma unroll
    for (int i = 0; i < 32; i += 8) {
        int c = cb + ty + i, k = kb + tx;
        if (c < Cpad && k < K) out[(size_t)c * K + k] = (bf16_t)tile[tx][ty + i];
    }
}

// out[r][c] = b_ctx[c] + freq[pid(r)][c]  (pre-fill for the fused atomics)
__global__ void init_out_kernel(const int* __restrict__ rel, const int* __restrict__ obj,
                                const float* __restrict__ b_ctx,
                                const float* __restrict__ freq,
                                float* __restrict__ out) {
    int r = blockIdx.x * 4 + (threadIdx.x >> 6);
    int c = threadIdx.x & 63;
    if (c < NRC) {
        int pid = obj[rel[2 * r]] * NOC + obj[rel[2 * r + 1]];
        out[(size_t)r * NRC + c] = b_ctx[c] + freq[(size_t)pid * NRC + c];
    }
}

// ---------------- GEMM1: C1 = relu(ec @ Wemb + b), bf16 out [8192][1024] ----------------
// (unchanged, known-good)

__global__ __launch_bounds__(256, 2) void gemm1_kernel(
    const bf16_t* __restrict__ A,    // [8192][512]
    const bf16_t* __restrict__ Bt,   // [1024][512]
    const float* __restrict__ bias,  // [1024]
    bf16_t* __restrict__ C)          // [8192][1024]
{
    __shared__ __align__(16) bf16_t As[128 * 64];
    __shared__ __align__(16) bf16_t Bs[128 * 64];
    const int tid = threadIdx.x;
    const int w = tid >> 6, lane = tid & 63;
    const int m0 = blockIdx.x * 128, n0 = blockIdx.y * 128;
    const int lrow = tid >> 3, lcs = tid & 7;
    const int wm = w & 1, wn = w >> 1;
    const int quad = lane >> 4, l16 = lane & 15;
    f32x4 acc[4][4] = {};

    for (int kt = 0; kt < HID / 64; ++kt) {
        const int k0 = kt * 64;
        #pragma unroll
        for (int j = 0; j < 4; ++j) {
            int ml = j * 32 + lrow;
            int cg = lcs ^ (ml & 7);
            async_copy16(A + (size_t)(m0 + ml) * HID + k0 + cg * 8, &As[ml * 64 + lcs * 8]);
        }
        #pragma unroll
        for (int j = 0; j < 4; ++j) {
            int nl = j * 32 + lrow;
            int cg = lcs ^ (nl & 7);
            async_copy16(Bt + (size_t)(n0 + nl) * HID + k0 + cg * 8, &Bs[nl * 64 + lcs * 8]);
        }
        __syncthreads();
        #pragma unroll
        for (int kb = 0; kb < 2; ++kb) {
            bf16x8 a[4], b[4];
            #pragma unroll
            for (int i = 0; i < 4; ++i) {
                int m = wm * 64 + i * 16 + l16;
                int ch = (kb * 4 + quad) ^ (m & 7);
                a[i] = *(const bf16x8*)&As[m * 64 + ch * 8];
            }
            #pragma unroll
            for (int i = 0; i < 4; ++i) {
                int n = wn * 64 + i * 16 + l16;
                int ch = (kb * 4 + quad) ^ (n & 7);
                b[i] = *(const bf16x8*)&Bs[n * 64 + ch * 8];
            }
            #pragma unroll
            for (int i = 0; i < 4; ++i)
                #pragma unroll
                for (int jj = 0; jj < 4; ++jj)
                    acc[i][jj] = __builtin_amdgcn_mfma_f32_16x16x32_bf16(a[i], b[jj], acc[i][jj], 0, 0, 0);
        }
        __syncthreads();
    }
    #pragma unroll
    for (int i = 0; i < 4; ++i) {
        int rbase = m0 + wm * 64 + i * 16 + quad * 4;
        #pragma unroll
        for (int jj = 0; jj < 4; ++jj) {
            int c = n0 + wn * 64 + jj * 16 + l16;
            float bv = bias[c];
            #pragma unroll
            for (int rr = 0; rr < 4; ++rr) {
                float v = acc[i][jj][rr] + bv;
                v = fmaxf(v, 0.0f);
                C[(size_t)(rbase + rr) * 1024 + c] = (bf16_t)v;
            }
        }
    }
}

// ---------------- GEMM2 fused, v3: 8-wave 256x128, counted-vmcnt pipeline ----------------
// Per K-tile: 2 sub-phases {stage3 -> (wait vmcnt(N), barrier) -> 12 ds_read -> 16 MFMA}.
// Steady-state wait = vmcnt(3): the 3 loads just issued may remain in flight; the 6 loads
// for the tile being computed (issued last tile) are guaranteed complete. Loads are never
// drained to 0 inside the loop. uni is prefetched to 64 VGPRs during tiles 0-1 (exact
// counted-wait arithmetic: t1=vmcnt(35), t2=vmcnt(19), t3+=vmcnt(3)).

__global__ __launch_bounds__(512, 2) void gemm2_fused_kernel(
    const bf16_t* __restrict__ C1,     // [8192][1024]
    const bf16_t* __restrict__ Bt,     // [4096][1024] (W_post_cat transposed)
    const bf16_t* __restrict__ Wctx_t, // [64][4096]   (W_ctx transposed, rows 51..63 zero)
    const int* __restrict__ rel,       // [32768][2]
    const float* __restrict__ bias,    // [4096] (b_cat)
    const float* __restrict__ uni,     // [32768][4096]
    float* __restrict__ out)           // [32768][51], pre-filled with b_ctx + freq
{
    // 96 KB LDS: A dbuf 2x32KB | B dbuf 2x16KB. Ss (256x128 bf16, 64KB) overlays A dbuf.
    __shared__ __align__(16) bf16_t lds[2 * 256 * 64 + 2 * 128 * 64];
    bf16_t* const Ab = lds;
    bf16_t* const Bb = lds + 2 * 256 * 64;
    bf16_t* const Ss = lds;

    const int tid = threadIdx.x;
    const int w = tid >> 6, lane = tid & 63;
    const int wm = w >> 1, wn = w & 1;          // 4M x 2N wave grid
    const int lrow = tid >> 3, lcs = tid & 7;   // 64 rows x 8 chunks staging
    const int quad = lane >> 4, l16 = lane & 15;
    const int m0 = blockIdx.x * 256;
    const int nbase = blockIdx.y * (NT * 128);

    int i0[4], i1[4];
    #pragma unroll
    for (int j = 0; j < 4; ++j) {
        int r = m0 + j * 64 + lrow;
        i0[j] = rel[2 * r];
        i1[j] = rel[2 * r + 1];
    }

    f32x4 acc2[4][2] = {};   // persistent across n-tiles

    for (int nt = 0; nt < NT; ++nt) {
        const int n0 = nbase + nt * 128;
        f32x4 acc[4][4] = {};
        float ureg[4][4][4];

        auto stageA = [&](bf16_t* dst, int j, int ktn) {
            int ml = j * 64 + lrow;
            int ridx = (ktn >= 8) ? i1[j] : i0[j];
            int cg = lcs ^ (ml & 7);
            async_copy16(C1 + (size_t)ridx * 1024 + ktn * 64 + cg * 8, dst + ml * 64 + lcs * 8);
        };
        auto stageB = [&](bf16_t* dst, int j, int ktn) {
            int nl = j * 64 + lrow;
            int cg = lcs ^ (nl & 7);
            async_copy16(Bt + (size_t)(n0 + nl) * 1024 + ktn * 64 + cg * 8, dst + nl * 64 + lcs * 8);
        };
        auto uni16 = [&](int c) {   // prefetch i=c slice of the uni tile (16 scalars)
            #pragma unroll
            for (int jj = 0; jj < 4; ++jj)
                #pragma unroll
                for (int rr = 0; rr < 4; ++rr)
                    ureg[c][jj][rr] =
                        uni[(size_t)(m0 + wm * 64 + c * 16 + quad * 4 + rr) * POOL
                            + n0 + wn * 64 + jj * 16 + l16];
        };
        auto phase = [&](const bf16_t* Asc, const bf16_t* Bsc, int ph) {
            bf16x8 a_[2][2], b_[4][2];
            #pragma unroll
            for (int il = 0; il < 2; ++il) {
                int m = wm * 64 + (ph * 2 + il) * 16 + l16;
                #pragma unroll
                for (int kb = 0; kb < 2; ++kb) {
                    int ch = (kb * 4 + quad) ^ (m & 7);
                    a_[il][kb] = *(const bf16x8*)&Asc[m * 64 + ch * 8];
                }
            }
            #pragma unroll
            for (int jj = 0; jj < 4; ++jj) {
                int n = wn * 64 + jj * 16 + l16;
                #pragma unroll
                for (int kb = 0; kb < 2; ++kb) {
                    int ch = (kb * 4 + quad) ^ (n & 7);
                    b_[jj][kb] = *(const bf16x8*)&Bsc[n * 64 + ch * 8];
                }
            }
            __builtin_amdgcn_s_setprio(1);
            #pragma unroll
            for (int il = 0; il < 2; ++il)
                #pragma unroll
                for (int jj = 0; jj < 4; ++jj)
                    #pragma unroll
                    for (int kb = 0; kb < 2; ++kb)
                        acc[ph * 2 + il][jj] = __builtin_amdgcn_mfma_f32_16x16x32_bf16(
                            a_[il][kb], b_[jj][kb], acc[ph * 2 + il][jj], 0, 0, 0);
            __builtin_amdgcn_s_setprio(0);
        };
        auto fence = [&]() {   // keep issue order of stage builtins vs uni loads
            asm volatile("" ::: "memory");
            __builtin_amdgcn_sched_barrier(0);
        };

        // ---- prologue: k-tile 0 -> buf0, full drain (only per-n-tile drain) ----
        stageA(Ab, 0, 0); stageA(Ab, 1, 0); stageA(Ab, 2, 0); stageA(Ab, 3, 0);
        stageB(Bb, 0, 0); stageB(Bb, 1, 0);
        __syncthreads();

        // ---- t0: compute buf0, stage t1 -> buf1, issue uni c0/c1 ----
        {
            bf16_t* An = Ab + 256 * 64; bf16_t* Bn = Bb + 128 * 64;
            stageA(An, 0, 1); stageA(An, 1, 1); stageB(Bn, 0, 1); fence();
            uni16(0); fence();
            phase(Ab, Bb, 0);
            stageA(An, 2, 1); stageA(An, 3, 1); stageB(Bn, 1, 1); fence();
            uni16(1); fence();
            phase(Ab, Bb, 1);
            __builtin_amdgcn_sched_barrier(0);
            __builtin_amdgcn_s_barrier();
            __builtin_amdgcn_sched_barrier(0);
        }
        // ---- t1: compute buf1, stage t2 -> buf0, issue uni c2/c3; wait vmcnt(35) ----
        {
            const bf16_t* Ac = Ab + 256 * 64; const bf16_t* Bc = Bb + 128 * 64;
            bf16_t* An = Ab; bf16_t* Bn = Bb;
            stageA(An, 0, 2); stageA(An, 1, 2); stageB(Bn, 0, 2); fence();
            uni16(2); fence();
            asm volatile("s_waitcnt vmcnt(35)" ::: "memory");
            __builtin_amdgcn_s_barrier();
            __builtin_amdgcn_sched_barrier(0);
            phase(Ac, Bc, 0);
            stageA(An, 2, 2); stageA(An, 3, 2); stageB(Bn, 1, 2); fence();
            uni16(3); fence();
            phase(Ac, Bc, 1);
            __builtin_amdgcn_sched_barrier(0);
            __builtin_amdgcn_s_barrier();
            __builtin_amdgcn_sched_barrier(0);
        }
        // ---- t2: compute buf0, stage t3 -> buf1; wait vmcnt(19) ----
        {
            const bf16_t* Ac = Ab; const bf16_t* Bc = Bb;
            bf16_t* An = Ab + 256 * 64; bf16_t* Bn = Bb + 128 * 64;
            stageA(An, 0, 3); stageA(An, 1, 3); stageB(Bn, 0, 3); fence();
            asm volatile("s_waitcnt vmcnt(19)" ::: "memory");
            __builtin_amdgcn_s_barrier();
            __builtin_amdgcn_sched_barrier(0);
            phase(Ac, Bc, 0);
            stageA(An, 2, 3); stageA(An, 3, 3); stageB(Bn, 1, 3); fence();
            phase(Ac, Bc, 1);
            __builtin_amdgcn_sched_barrier(0);
            __builtin_amdgcn_s_barrier();
            __builtin_amdgcn_sched_barrier(0);
        }
        // ---- t3..t14 steady state: wait vmcnt(3) ----
        for (int kt = 3; kt < 15; ++kt) {
            const int cc = kt & 1;
            const bf16_t* Ac = Ab + cc * 256 * 64; const bf16_t* Bc = Bb + cc * 128 * 64;
            bf16_t* An = Ab + (cc ^ 1) * 256 * 64; bf16_t* Bn = Bb + (cc ^ 1) * 128 * 64;
            stageA(An, 0, kt + 1); stageA(An, 1, kt + 1); stageB(Bn, 0, kt + 1); fence();
            asm volatile("s_waitcnt vmcnt(3)" ::: "memory");
            __builtin_amdgcn_s_barrier();
            __builtin_amdgcn_sched_barrier(0);
            phase(Ac, Bc, 0);
            stageA(An, 2, kt + 1); stageA(An, 3, kt + 1); stageB(Bn, 1, kt + 1); fence();
            phase(Ac, Bc, 1);
            __builtin_amdgcn_sched_barrier(0);
            __builtin_amdgcn_s_barrier();
            __builtin_amdgcn_sched_barrier(0);
        }
        // ---- t15 peeled: no staging; wait vmcnt(0) ----
        {
            const bf16_t* Ac = Ab + 256 * 64; const bf16_t* Bc = Bb + 128 * 64;
            asm volatile("s_waitcnt vmcnt(0)" ::: "memory");
            __builtin_amdgcn_s_barrier();
            __builtin_amdgcn_sched_barrier(0);
            phase(Ac, Bc, 0);
            phase(Ac, Bc, 1);
        }
        __syncthreads();   // all reads done before Ss overlays the A buffers

        // ---- Epilogue A: scaled = (acc + b_cat) * uni -> bf16 -> Ss [256][128] swizzled ----
        #pragma unroll
        for (int i = 0; i < 4; ++i) {
            #pragma unroll
            for (int jj = 0; jj < 4; ++jj) {
                int col = wn * 64 + jj * 16 + l16;
                float bv = bias[n0 + col];
                #pragma unroll
                for (int rr = 0; rr < 4; ++rr) {
                    int lm = wm * 64 + i * 16 + quad * 4 + rr;
                    float v = (acc[i][jj][rr] + bv) * ureg[i][jj][rr];
                    int ch = (col >> 3) ^ (lm & 15);
                    Ss[lm * 128 + ch * 8 + (col & 7)] = (bf16_t)v;
                }
            }
        }
        __syncthreads();

        // ---- Epilogue B: acc2 += Ss(256x128) @ Wctx[n0:n0+128][0:64] ----
        #pragma unroll
        for (int kb = 0; kb < 4; ++kb) {   // K = 128, steps of 32
            bf16x8 a2[4], b2[2];
            #pragma unroll
            for (int i = 0; i < 4; ++i) {
                int m = wm * 64 + i * 16 + l16;
                int ch = (kb * 4 + quad) ^ (m & 15);
                a2[i] = *(const bf16x8*)&Ss[m * 128 + ch * 8];
            }
            #pragma unroll
            for (int jj = 0; jj < 2; ++jj) {
                int c = wn * 32 + jj * 16 + l16;   // class index 0..63
                b2[jj] = *(const bf16x8*)&Wctx_t[(size_t)c * POOL + n0 + kb * 32 + quad * 8];
            }
            #pragma unroll
            for (int i = 0; i < 4; ++i)
                #pragma unroll
                for (int jj = 0; jj < 2; ++jj)
                    acc2[i][jj] = __builtin_amdgcn_mfma_f32_16x16x32_bf16(a2[i], b2[jj], acc2[i][jj], 0, 0, 0);
        }
        __syncthreads();   // Ss reads done before next n-tile restages the A buffers
    }

    // ---- Final: NSPLIT-way atomic add of persistent partials ----
    #pragma unroll
    for (int i = 0; i < 4; ++i) {
        int rbase = m0 + wm * 64 + i * 16 + quad * 4;
        #pragma unroll
        for (int jj = 0; jj < 2; ++jj) {
            int c = wn * 32 + jj * 16 + l16;
            if (c < NRC) {
                #pragma unroll
                for (int rr = 0; rr < 4; ++rr)
                    atomicAdd(&out[(size_t)(rbase + rr) * NRC + c], acc2[i][jj][rr]);
            }
        }
    }
}

// ---------------- launcher ----------------

extern "C" void kernel_launch(void* const* d_in, const int* in_sizes, int n_in,
                              void* d_out, int out_size, void* d_ws, size_t ws_size,
                              hipStream_t stream) {
    const float* edge_ctx = (const float*)d_in[0];
    const float* uni      = (const float*)d_in[1];
    const int*   rel      = (const int*)d_in[2];
    const int*   obj      = (const int*)d_in[3];
    const float* W_emb    = (const float*)d_in[4];
    const float* b_emb    = (const float*)d_in[5];
    const float* W_cat    = (const float*)d_in[6];
    const float* b_cat    = (const float*)d_in[7];
    const float* W_ctx    = (const float*)d_in[8];
    const float* b_ctx    = (const float*)d_in[9];
    const float* freq     = (const float*)d_in[10];
    float* out = (float*)d_out;

    char* p = (char*)d_ws;
    bf16_t* C1     = (bf16_t*)p; p += (size_t)N_OBJ * 1024 * 2;
    bf16_t* ecb    = (bf16_t*)p; p += (size_t)N_OBJ * HID * 2;
    bf16_t* Wemb_t = (bf16_t*)p; p += (size_t)1024 * HID * 2;
    bf16_t* Wcat_t = (bf16_t*)p; p += (size_t)POOL * 1024 * 2;
    bf16_t* Wctx_t = (bf16_t*)p; p += (size_t)64 * POOL * 2;

    convert_bf16_kernel<<<2048, 256, 0, stream>>>(edge_ctx, ecb, N_OBJ * HID / 4);
    transpose_bf16_kernel<<<dim3(1024 / 32, HID / 32), dim3(32, 8), 0, stream>>>(W_emb, Wemb_t, HID, 1024, 1024);
    transpose_bf16_kernel<<<dim3(POOL / 32, 1024 / 32), dim3(32, 8), 0, stream>>>(W_cat, Wcat_t, 1024, POOL, POOL);
    transpose_bf16_kernel<<<dim3(2, POOL / 32), dim3(32, 8), 0, stream>>>(W_ctx, Wctx_t, POOL, NRC, 64);
    init_out_kernel<<<N_REL / 4, 256, 0, stream>>>(rel, obj, b_ctx, freq, out);

    gemm1_kernel<<<dim3(N_OBJ / 128, 1024 / 128), 256, 0, stream>>>(ecb, Wemb_t, b_emb, C1);
    gemm2_fused_kernel<<<dim3(N_REL / 256, NSPLIT), 512, 0, stream>>>(C1, Wcat_t, Wctx_t, rel, b_cat, uni, out);
}

// Round 4
// 1457.819 us; speedup vs baseline: 1.1681x; 1.1681x over previous
//
#include <hip/hip_runtime.h>
#include <hip/hip_bf16.h>

#define N_OBJ 8192
#define N_REL 32768
#define HID   512
#define POOL  4096
#define NOC   151
#define NRC   51

// gemm2: 256x128 tiles, 8 waves; each block walks NT n-tiles, NSPLIT blocks per m-row.
#define NSPLIT 2
#define NT    (POOL / 128 / NSPLIT)   // 16

typedef __bf16 bf16_t;
typedef __attribute__((ext_vector_type(8))) __bf16 bf16x8;
typedef __attribute__((ext_vector_type(4))) __bf16 bf16x4;
typedef __attribute__((ext_vector_type(4))) float f32x4;

// Async global->LDS, 16B per lane. LDS dest semantics: wave-uniform base + lane*16.
__device__ __forceinline__ void async_copy16(const void* g, void* l) {
    __builtin_amdgcn_global_load_lds((__attribute__((address_space(1))) void*)g,
                                     (__attribute__((address_space(3))) void*)l,
                                     16, 0, 0);
}

// ---------------- small prep kernels ----------------

__global__ void convert_bf16_kernel(const float* __restrict__ in,
                                    bf16_t* __restrict__ out, int n4) {
    int i = blockIdx.x * blockDim.x + threadIdx.x;
    int stride = gridDim.x * blockDim.x;
    for (; i < n4; i += stride) {
        float4 v = ((const float4*)in)[i];
        bf16x4 o;
        o[0] = (bf16_t)v.x; o[1] = (bf16_t)v.y; o[2] = (bf16_t)v.z; o[3] = (bf16_t)v.w;
        ((bf16x4*)out)[i] = o;
    }
}

// in: f32 [K][C] row-major -> out: bf16 [Cpad][K] (transposed, zero-padded in C)
__global__ void transpose_bf16_kernel(const float* __restrict__ in,
                                      bf16_t* __restrict__ out,
                                      int K, int C, int Cpad) {
    __shared__ float tile[32][33];
    int cb = blockIdx.x * 32, kb = blockIdx.y * 32;
    int tx = threadIdx.x, ty = threadIdx.y; // 32 x 8
    #pragma unroll
    for (int i = 0; i < 32; i += 8) {
        int k = kb + ty + i, c = cb + tx;
        float v = (k < K && c < C) ? in[(size_t)k * C + c] : 0.0f;
        tile[ty + i][tx] = v;
    }
    __syncthreads();
    #pragma unroll
    for (int i = 0; i < 32; i += 8) {
        int c = cb + ty + i, k = kb + tx;
        if (c < Cpad && k < K) out[(size_t)c * K + k] = (bf16_t)tile[tx][ty + i];
    }
}

// out[r][c] = b_ctx[c] + freq[pid(r)][c]  (pre-fill for the fused atomics)
__global__ void init_out_kernel(const int* __restrict__ rel, const int* __restrict__ obj,
                                const float* __restrict__ b_ctx,
                                const float* __restrict__ freq,
                                float* __restrict__ out) {
    int r = blockIdx.x * 4 + (threadIdx.x >> 6);
    int c = threadIdx.x & 63;
    if (c < NRC) {
        int pid = obj[rel[2 * r]] * NOC + obj[rel[2 * r + 1]];
        out[(size_t)r * NRC + c] = b_ctx[c] + freq[(size_t)pid * NRC + c];
    }
}

// ---------------- GEMM1: C1 = relu(ec @ Wemb + b), bf16 out [8192][1024] ----------------
// (unchanged, known-good)

__global__ __launch_bounds__(256, 2) void gemm1_kernel(
    const bf16_t* __restrict__ A,    // [8192][512]
    const bf16_t* __restrict__ Bt,   // [1024][512]
    const float* __restrict__ bias,  // [1024]
    bf16_t* __restrict__ C)          // [8192][1024]
{
    __shared__ __align__(16) bf16_t As[128 * 64];
    __shared__ __align__(16) bf16_t Bs[128 * 64];
    const int tid = threadIdx.x;
    const int w = tid >> 6, lane = tid & 63;
    const int m0 = blockIdx.x * 128, n0 = blockIdx.y * 128;
    const int lrow = tid >> 3, lcs = tid & 7;
    const int wm = w & 1, wn = w >> 1;
    const int quad = lane >> 4, l16 = lane & 15;
    f32x4 acc[4][4] = {};

    for (int kt = 0; kt < HID / 64; ++kt) {
        const int k0 = kt * 64;
        #pragma unroll
        for (int j = 0; j < 4; ++j) {
            int ml = j * 32 + lrow;
            int cg = lcs ^ (ml & 7);
            async_copy16(A + (size_t)(m0 + ml) * HID + k0 + cg * 8, &As[ml * 64 + lcs * 8]);
        }
        #pragma unroll
        for (int j = 0; j < 4; ++j) {
            int nl = j * 32 + lrow;
            int cg = lcs ^ (nl & 7);
            async_copy16(Bt + (size_t)(n0 + nl) * HID + k0 + cg * 8, &Bs[nl * 64 + lcs * 8]);
        }
        __syncthreads();
        #pragma unroll
        for (int kb = 0; kb < 2; ++kb) {
            bf16x8 a[4], b[4];
            #pragma unroll
            for (int i = 0; i < 4; ++i) {
                int m = wm * 64 + i * 16 + l16;
                int ch = (kb * 4 + quad) ^ (m & 7);
                a[i] = *(const bf16x8*)&As[m * 64 + ch * 8];
            }
            #pragma unroll
            for (int i = 0; i < 4; ++i) {
                int n = wn * 64 + i * 16 + l16;
                int ch = (kb * 4 + quad) ^ (n & 7);
                b[i] = *(const bf16x8*)&Bs[n * 64 + ch * 8];
            }
            #pragma unroll
            for (int i = 0; i < 4; ++i)
                #pragma unroll
                for (int jj = 0; jj < 4; ++jj)
                    acc[i][jj] = __builtin_amdgcn_mfma_f32_16x16x32_bf16(a[i], b[jj], acc[i][jj], 0, 0, 0);
        }
        __syncthreads();
    }
    #pragma unroll
    for (int i = 0; i < 4; ++i) {
        int rbase = m0 + wm * 64 + i * 16 + quad * 4;
        #pragma unroll
        for (int jj = 0; jj < 4; ++jj) {
            int c = n0 + wn * 64 + jj * 16 + l16;
            float bv = bias[c];
            #pragma unroll
            for (int rr = 0; rr < 4; ++rr) {
                float v = acc[i][jj][rr] + bv;
                v = fmaxf(v, 0.0f);
                C[(size_t)(rbase + rr) * 1024 + c] = (bf16_t)v;
            }
        }
    }
}

// ---------------- GEMM2 fused, v5: 8-wave 256x128, counted-vmcnt, minimal live set ----------------
// launch_bounds(512,2): 256-reg unified budget; live set ~200 -> no spill (verify via
// WRITE_SIZE). Steady state waits vmcnt(3) (never 0 inside loop); peeled t15 waits
// vmcnt(0). uni is read directly in Epilogue A (no ureg prefetch -> no spill risk).

__global__ __launch_bounds__(512, 2) void gemm2_fused_kernel(
    const bf16_t* __restrict__ C1,     // [8192][1024]
    const bf16_t* __restrict__ Bt,     // [4096][1024] (W_post_cat transposed)
    const bf16_t* __restrict__ Wctx_t, // [64][4096]   (W_ctx transposed, rows 51..63 zero)
    const int* __restrict__ rel,       // [32768][2]
    const float* __restrict__ bias,    // [4096] (b_cat)
    const float* __restrict__ uni,     // [32768][4096]
    float* __restrict__ out)           // [32768][51], pre-filled with b_ctx + freq
{
    // 96 KB LDS: A dbuf 2x32KB | B dbuf 2x16KB. Ss (256x128 bf16, 64KB) overlays A dbuf.
    __shared__ __align__(16) bf16_t lds[2 * 256 * 64 + 2 * 128 * 64];
    bf16_t* const Ab = lds;
    bf16_t* const Bb = lds + 2 * 256 * 64;
    bf16_t* const Ss = lds;

    const int tid = threadIdx.x;
    const int w = tid >> 6, lane = tid & 63;
    const int wm = w >> 1, wn = w & 1;          // 4M x 2N wave grid
    const int lrow = tid >> 3, lcs = tid & 7;   // 64 rows x 8 chunks staging
    const int quad = lane >> 4, l16 = lane & 15;
    const int m0 = blockIdx.x * 256;
    const int nbase = blockIdx.y * (NT * 128);

    int i0[4], i1[4];
    #pragma unroll
    for (int j = 0; j < 4; ++j) {
        int r = m0 + j * 64 + lrow;
        i0[j] = rel[2 * r];
        i1[j] = rel[2 * r + 1];
    }

    f32x4 acc2[4][2] = {};   // persistent across n-tiles

    for (int nt = 0; nt < NT; ++nt) {
        const int n0 = nbase + nt * 128;
        f32x4 acc[4][4] = {};

        auto stageA = [&](bf16_t* dst, int j, int ktn) {
            int ml = j * 64 + lrow;
            int ridx = (ktn >= 8) ? i1[j] : i0[j];
            int cg = lcs ^ (ml & 7);
            async_copy16(C1 + (size_t)ridx * 1024 + ktn * 64 + cg * 8, dst + ml * 64 + lcs * 8);
        };
        auto stageB = [&](bf16_t* dst, int j, int ktn) {
            int nl = j * 64 + lrow;
            int cg = lcs ^ (nl & 7);
            async_copy16(Bt + (size_t)(n0 + nl) * 1024 + ktn * 64 + cg * 8, dst + nl * 64 + lcs * 8);
        };
        auto phase = [&](const bf16_t* Asc, const bf16_t* Bsc, int ph) {
            #pragma unroll
            for (int kb = 0; kb < 2; ++kb) {
                bf16x8 a_[2], b_[4];
                #pragma unroll
                for (int il = 0; il < 2; ++il) {
                    int m = wm * 64 + (ph * 2 + il) * 16 + l16;
                    int ch = (kb * 4 + quad) ^ (m & 7);
                    a_[il] = *(const bf16x8*)&Asc[m * 64 + ch * 8];
                }
                #pragma unroll
                for (int jj = 0; jj < 4; ++jj) {
                    int n = wn * 64 + jj * 16 + l16;
                    int ch = (kb * 4 + quad) ^ (n & 7);
                    b_[jj] = *(const bf16x8*)&Bsc[n * 64 + ch * 8];
                }
                __builtin_amdgcn_s_setprio(1);
                #pragma unroll
                for (int il = 0; il < 2; ++il)
                    #pragma unroll
                    for (int jj = 0; jj < 4; ++jj)
                        acc[ph * 2 + il][jj] = __builtin_amdgcn_mfma_f32_16x16x32_bf16(
                            a_[il], b_[jj], acc[ph * 2 + il][jj], 0, 0, 0);
                __builtin_amdgcn_s_setprio(0);
            }
        };
        auto fence = [&]() {
            asm volatile("" ::: "memory");
            __builtin_amdgcn_sched_barrier(0);
        };

        // ---- prologue: k-tile 0 -> buf0, full drain ----
        stageA(Ab, 0, 0); stageA(Ab, 1, 0); stageA(Ab, 2, 0); stageA(Ab, 3, 0);
        stageB(Bb, 0, 0); stageB(Bb, 1, 0);
        __syncthreads();

        // ---- t0: compute buf0, stage t1 -> buf1 (no wait: prologue drained) ----
        {
            bf16_t* An = Ab + 256 * 64; bf16_t* Bn = Bb + 128 * 64;
            stageA(An, 0, 1); stageA(An, 1, 1); stageB(Bn, 0, 1); fence();
            phase(Ab, Bb, 0);
            stageA(An, 2, 1); stageA(An, 3, 1); stageB(Bn, 1, 1); fence();
            phase(Ab, Bb, 1);
            __builtin_amdgcn_sched_barrier(0);
            __builtin_amdgcn_s_barrier();
            __builtin_amdgcn_sched_barrier(0);
        }
        // ---- t1..t14 steady state: wait vmcnt(3) ----
        for (int kt = 1; kt <= 14; ++kt) {
            const int cc = kt & 1;
            const bf16_t* Ac = Ab + cc * 256 * 64; const bf16_t* Bc = Bb + cc * 128 * 64;
            bf16_t* An = Ab + (cc ^ 1) * 256 * 64; bf16_t* Bn = Bb + (cc ^ 1) * 128 * 64;
            stageA(An, 0, kt + 1); stageA(An, 1, kt + 1); stageB(Bn, 0, kt + 1); fence();
            asm volatile("s_waitcnt vmcnt(3)" ::: "memory");
            __builtin_amdgcn_s_barrier();
            __builtin_amdgcn_sched_barrier(0);
            phase(Ac, Bc, 0);
            stageA(An, 2, kt + 1); stageA(An, 3, kt + 1); stageB(Bn, 1, kt + 1); fence();
            phase(Ac, Bc, 1);
            __builtin_amdgcn_sched_barrier(0);
            __builtin_amdgcn_s_barrier();
            __builtin_amdgcn_sched_barrier(0);
        }
        // ---- t15 peeled: no staging; wait vmcnt(0) ----
        {
            const bf16_t* Ac = Ab + 256 * 64; const bf16_t* Bc = Bb + 128 * 64;
            asm volatile("s_waitcnt vmcnt(0)" ::: "memory");
            __builtin_amdgcn_s_barrier();
            __builtin_amdgcn_sched_barrier(0);
            phase(Ac, Bc, 0);
            phase(Ac, Bc, 1);
        }
        __syncthreads();   // all reads done before Ss overlays the A buffers

        // ---- Epilogue A: scaled = (acc + b_cat) * uni -> bf16 -> Ss [256][128] swizzled ----
        #pragma unroll
        for (int i = 0; i < 4; ++i) {
            #pragma unroll
            for (int jj = 0; jj < 4; ++jj) {
                int col = wn * 64 + jj * 16 + l16;
                float bv = bias[n0 + col];
                #pragma unroll
                for (int rr = 0; rr < 4; ++rr) {
                    int lm = wm * 64 + i * 16 + quad * 4 + rr;
                    float v = (acc[i][jj][rr] + bv) * uni[(size_t)(m0 + lm) * POOL + n0 + col];
                    int ch = (col >> 3) ^ (lm & 15);
                    Ss[lm * 128 + ch * 8 + (col & 7)] = (bf16_t)v;
                }
            }
        }
        __syncthreads();

        // ---- Epilogue B: acc2 += Ss(256x128) @ Wctx[n0:n0+128][0:64] ----
        #pragma unroll
        for (int kb = 0; kb < 4; ++kb) {   // K = 128, steps of 32
            bf16x8 a2[4], b2[2];
            #pragma unroll
            for (int i = 0; i < 4; ++i) {
                int m = wm * 64 + i * 16 + l16;
                int ch = (kb * 4 + quad) ^ (m & 15);
                a2[i] = *(const bf16x8*)&Ss[m * 128 + ch * 8];
            }
            #pragma unroll
            for (int jj = 0; jj < 2; ++jj) {
                int c = wn * 32 + jj * 16 + l16;   // class index 0..63
                b2[jj] = *(const bf16x8*)&Wctx_t[(size_t)c * POOL + n0 + kb * 32 + quad * 8];
            }
            #pragma unroll
            for (int i = 0; i < 4; ++i)
                #pragma unroll
                for (int jj = 0; jj < 2; ++jj)
                    acc2[i][jj] = __builtin_amdgcn_mfma_f32_16x16x32_bf16(a2[i], b2[jj], acc2[i][jj], 0, 0, 0);
        }
        __syncthreads();   // Ss reads done before next n-tile restages the A buffers
    }

    // ---- Final: NSPLIT-way atomic add of persistent partials ----
    #pragma unroll
    for (int i = 0; i < 4; ++i) {
        int rbase = m0 + wm * 64 + i * 16 + quad * 4;
        #pragma unroll
        for (int jj = 0; jj < 2; ++jj) {
            int c = wn * 32 + jj * 16 + l16;
            if (c < NRC) {
                #pragma unroll
                for (int rr = 0; rr < 4; ++rr)
                    atomicAdd(&out[(size_t)(rbase + rr) * NRC + c], acc2[i][jj][rr]);
            }
        }
    }
}

// ---------------- launcher ----------------

extern "C" void kernel_launch(void* const* d_in, const int* in_sizes, int n_in,
                              void* d_out, int out_size, void* d_ws, size_t ws_size,
                              hipStream_t stream) {
    const float* edge_ctx = (const float*)d_in[0];
    const float* uni      = (const float*)d_in[1];
    const int*   rel      = (const int*)d_in[2];
    const int*   obj      = (const int*)d_in[3];
    const float* W_emb    = (const float*)d_in[4];
    const float* b_emb    = (const float*)d_in[5];
    const float* W_cat    = (const float*)d_in[6];
    const float* b_cat    = (const float*)d_in[7];
    const float* W_ctx    = (const float*)d_in[8];
    const float* b_ctx    = (const float*)d_in[9];
    const float* freq     = (const float*)d_in[10];
    float* out = (float*)d_out;

    char* p = (char*)d_ws;
    bf16_t* C1     = (bf16_t*)p; p += (size_t)N_OBJ * 1024 * 2;
    bf16_t* ecb    = (bf16_t*)p; p += (size_t)N_OBJ * HID * 2;
    bf16_t* Wemb_t = (bf16_t*)p; p += (size_t)1024 * HID * 2;
    bf16_t* Wcat_t = (bf16_t*)p; p += (size_t)POOL * 1024 * 2;
    bf16_t* Wctx_t = (bf16_t*)p; p += (size_t)64 * POOL * 2;

    convert_bf16_kernel<<<2048, 256, 0, stream>>>(edge_ctx, ecb, N_OBJ * HID / 4);
    transpose_bf16_kernel<<<dim3(1024 / 32, HID / 32), dim3(32, 8), 0, stream>>>(W_emb, Wemb_t, HID, 1024, 1024);
    transpose_bf16_kernel<<<dim3(POOL / 32, 1024 / 32), dim3(32, 8), 0, stream>>>(W_cat, Wcat_t, 1024, POOL, POOL);
    transpose_bf16_kernel<<<dim3(2, POOL / 32), dim3(32, 8), 0, stream>>>(W_ctx, Wctx_t, POOL, NRC, 64);
    init_out_kernel<<<N_REL / 4, 256, 0, stream>>>(rel, obj, b_ctx, freq, out);

    gemm1_kernel<<<dim3(N_OBJ / 128, 1024 / 128), 256, 0, stream>>>(ecb, Wemb_t, b_emb, C1);
    gemm2_fused_kernel<<<dim3(N_REL / 256, NSPLIT), 512, 0, stream>>>(C1, Wcat_t, Wctx_t, rel, b_cat, uni, out);
}

// Round 5
// 1425.423 us; speedup vs baseline: 1.1946x; 1.0227x over previous
//
#include <hip/hip_runtime.h>
#include <hip/hip_bf16.h>

#define N_OBJ 8192
#define N_REL 32768
#define HID   512
#define POOL  4096
#define NOC   151
#define NRC   51

// gemm2: each block walks NWALK consecutive n-tiles (acc2 persistent in regs),
// NB = POOL/128/NWALK blocks contribute atomically per output row.
#define NWALK 4
#define NB    (POOL / 128 / NWALK)   // 8

typedef __bf16 bf16_t;
typedef __attribute__((ext_vector_type(8))) __bf16 bf16x8;
typedef __attribute__((ext_vector_type(4))) __bf16 bf16x4;
typedef __attribute__((ext_vector_type(4))) float f32x4;

// Async global->LDS, 16B per lane. LDS dest semantics: wave-uniform base + lane*16.
__device__ __forceinline__ void async_copy16(const void* g, void* l) {
    __builtin_amdgcn_global_load_lds((__attribute__((address_space(1))) void*)g,
                                     (__attribute__((address_space(3))) void*)l,
                                     16, 0, 0);
}

// ---------------- small prep kernels ----------------

__global__ void convert_bf16_kernel(const float* __restrict__ in,
                                    bf16_t* __restrict__ out, int n4) {
    int i = blockIdx.x * blockDim.x + threadIdx.x;
    int stride = gridDim.x * blockDim.x;
    for (; i < n4; i += stride) {
        float4 v = ((const float4*)in)[i];
        bf16x4 o;
        o[0] = (bf16_t)v.x; o[1] = (bf16_t)v.y; o[2] = (bf16_t)v.z; o[3] = (bf16_t)v.w;
        ((bf16x4*)out)[i] = o;
    }
}

// in: f32 [K][C] row-major -> out: bf16 [Cpad][K] (transposed, zero-padded in C)
__global__ void transpose_bf16_kernel(const float* __restrict__ in,
                                      bf16_t* __restrict__ out,
                                      int K, int C, int Cpad) {
    __shared__ float tile[32][33];
    int cb = blockIdx.x * 32, kb = blockIdx.y * 32;
    int tx = threadIdx.x, ty = threadIdx.y; // 32 x 8
    #pragma unroll
    for (int i = 0; i < 32; i += 8) {
        int k = kb + ty + i, c = cb + tx;
        float v = (k < K && c < C) ? in[(size_t)k * C + c] : 0.0f;
        tile[ty + i][tx] = v;
    }
    __syncthreads();
    #pragma unroll
    for (int i = 0; i < 32; i += 8) {
        int c = cb + ty + i, k = kb + tx;
        if (c < Cpad && k < K) out[(size_t)c * K + k] = (bf16_t)tile[tx][ty + i];
    }
}

// out[r][c] = b_ctx[c] + freq[pid(r)][c]  (pre-fill for the fused atomics)
__global__ void init_out_kernel(const int* __restrict__ rel, const int* __restrict__ obj,
                                const float* __restrict__ b_ctx,
                                const float* __restrict__ freq,
                                float* __restrict__ out) {
    int r = blockIdx.x * 4 + (threadIdx.x >> 6);
    int c = threadIdx.x & 63;
    if (c < NRC) {
        int pid = obj[rel[2 * r]] * NOC + obj[rel[2 * r + 1]];
        out[(size_t)r * NRC + c] = b_ctx[c] + freq[(size_t)pid * NRC + c];
    }
}

// ---------------- GEMM1: C1 = relu(ec @ Wemb + b), bf16 out [8192][1024] ----------------
// (unchanged, known-good)

__global__ __launch_bounds__(256, 2) void gemm1_kernel(
    const bf16_t* __restrict__ A,    // [8192][512]
    const bf16_t* __restrict__ Bt,   // [1024][512]
    const float* __restrict__ bias,  // [1024]
    bf16_t* __restrict__ C)          // [8192][1024]
{
    __shared__ __align__(16) bf16_t As[128 * 64];
    __shared__ __align__(16) bf16_t Bs[128 * 64];
    const int tid = threadIdx.x;
    const int w = tid >> 6, lane = tid & 63;
    const int m0 = blockIdx.x * 128, n0 = blockIdx.y * 128;
    const int lrow = tid >> 3, lcs = tid & 7;
    const int wm = w & 1, wn = w >> 1;
    const int quad = lane >> 4, l16 = lane & 15;
    f32x4 acc[4][4] = {};

    for (int kt = 0; kt < HID / 64; ++kt) {
        const int k0 = kt * 64;
        #pragma unroll
        for (int j = 0; j < 4; ++j) {
            int ml = j * 32 + lrow;
            int cg = lcs ^ (ml & 7);
            async_copy16(A + (size_t)(m0 + ml) * HID + k0 + cg * 8, &As[ml * 64 + lcs * 8]);
        }
        #pragma unroll
        for (int j = 0; j < 4; ++j) {
            int nl = j * 32 + lrow;
            int cg = lcs ^ (nl & 7);
            async_copy16(Bt + (size_t)(n0 + nl) * HID + k0 + cg * 8, &Bs[nl * 64 + lcs * 8]);
        }
        __syncthreads();
        #pragma unroll
        for (int kb = 0; kb < 2; ++kb) {
            bf16x8 a[4], b[4];
            #pragma unroll
            for (int i = 0; i < 4; ++i) {
                int m = wm * 64 + i * 16 + l16;
                int ch = (kb * 4 + quad) ^ (m & 7);
                a[i] = *(const bf16x8*)&As[m * 64 + ch * 8];
            }
            #pragma unroll
            for (int i = 0; i < 4; ++i) {
                int n = wn * 64 + i * 16 + l16;
                int ch = (kb * 4 + quad) ^ (n & 7);
                b[i] = *(const bf16x8*)&Bs[n * 64 + ch * 8];
            }
            #pragma unroll
            for (int i = 0; i < 4; ++i)
                #pragma unroll
                for (int jj = 0; jj < 4; ++jj)
                    acc[i][jj] = __builtin_amdgcn_mfma_f32_16x16x32_bf16(a[i], b[jj], acc[i][jj], 0, 0, 0);
        }
        __syncthreads();
    }
    #pragma unroll
    for (int i = 0; i < 4; ++i) {
        int rbase = m0 + wm * 64 + i * 16 + quad * 4;
        #pragma unroll
        for (int jj = 0; jj < 4; ++jj) {
            int c = n0 + wn * 64 + jj * 16 + l16;
            float bv = bias[c];
            #pragma unroll
            for (int rr = 0; rr < 4; ++rr) {
                float v = acc[i][jj][rr] + bv;
                v = fmaxf(v, 0.0f);
                C[(size_t)(rbase + rr) * 1024 + c] = (bf16_t)v;
            }
        }
    }
}

// ---------------- GEMM2 fused, v6: R0 structure + n-persistence + XCD swizzle ----------------
// 128x128 tile, 4 waves, 32 KB LDS single-buffer (occupancy-first: R0's proven regime).
// Each block walks NWALK=4 consecutive n-tiles; acc2 (51-class partials) persists in
// registers -> 8-way atomics instead of 32-way. 1D grid of 2048 blocks with bijective
// XCD swizzle: one n-group x all-m per XCD chunk -> Bt/Wctx slice L2-resident.

__global__ __launch_bounds__(256, 2) void gemm2_fused_kernel(
    const bf16_t* __restrict__ C1,     // [8192][1024]
    const bf16_t* __restrict__ Bt,     // [4096][1024] (W_post_cat transposed)
    const bf16_t* __restrict__ Wctx_t, // [64][4096]   (W_ctx transposed, rows 51..63 zero)
    const int* __restrict__ rel,       // [32768][2]
    const float* __restrict__ bias,    // [4096] (b_cat)
    const float* __restrict__ uni,     // [32768][4096]
    float* __restrict__ out)           // [32768][51], pre-filled with b_ctx + freq
{
    // 32 KB LDS: As/Bs during the K-loop, reused as the scaled tile Ss afterwards.
    __shared__ __align__(16) bf16_t smem[128 * 64 * 2];
    bf16_t* As = smem;
    bf16_t* Bs = smem + 128 * 64;
    bf16_t* Ss = smem;                 // [128][128] bf16, XOR-swizzled 16B chunks

    const int tid = threadIdx.x;
    const int w = tid >> 6, lane = tid & 63;
    // XCD-aware bijective swizzle (nwg = 2048, divisible by 8): chunk of 256
    // consecutive wgids = all m-blocks for ONE n-group -> lands on one XCD.
    const int orig = blockIdx.x;
    const int wgid = (orig & 7) * (2048 / 8) + (orig >> 3);
    const int mb = wgid & 255, nb = wgid >> 8;
    const int m0 = mb * 128;
    const int nbase = nb * (NWALK * 128);

    const int lrow = tid >> 3, lcs = tid & 7;
    const int wm = w & 1, wn = w >> 1;
    const int quad = lane >> 4, l16 = lane & 15;

    int i0[4], i1[4];
    #pragma unroll
    for (int j = 0; j < 4; ++j) {
        int r = m0 + j * 32 + lrow;
        i0[j] = rel[2 * r];
        i1[j] = rel[2 * r + 1];
    }

    f32x4 acc2[4][2] = {};   // persistent across the NWALK n-tiles

    for (int nt = 0; nt < NWALK; ++nt) {
        const int n0 = nbase + nt * 128;
        f32x4 acc[4][4] = {};

        for (int kt = 0; kt < 1024 / 64; ++kt) {
            const int k0 = kt * 64;
            const bool tail = (k0 >= 512);
            #pragma unroll
            for (int j = 0; j < 4; ++j) {
                int ml = j * 32 + lrow;
                int ridx = tail ? i1[j] : i0[j];
                int cg = lcs ^ (ml & 7);
                async_copy16(C1 + (size_t)ridx * 1024 + k0 + cg * 8, &As[ml * 64 + lcs * 8]);
            }
            #pragma unroll
            for (int j = 0; j < 4; ++j) {
                int nl = j * 32 + lrow;
                int cg = lcs ^ (nl & 7);
                async_copy16(Bt + (size_t)(n0 + nl) * 1024 + k0 + cg * 8, &Bs[nl * 64 + lcs * 8]);
            }
            __syncthreads();
            #pragma unroll
            for (int kb = 0; kb < 2; ++kb) {
                bf16x8 a[4], b[4];
                #pragma unroll
                for (int i = 0; i < 4; ++i) {
                    int m = wm * 64 + i * 16 + l16;
                    int ch = (kb * 4 + quad) ^ (m & 7);
                    a[i] = *(const bf16x8*)&As[m * 64 + ch * 8];
                }
                #pragma unroll
                for (int i = 0; i < 4; ++i) {
                    int n = wn * 64 + i * 16 + l16;
                    int ch = (kb * 4 + quad) ^ (n & 7);
                    b[i] = *(const bf16x8*)&Bs[n * 64 + ch * 8];
                }
                #pragma unroll
                for (int i = 0; i < 4; ++i)
                    #pragma unroll
                    for (int jj = 0; jj < 4; ++jj)
                        acc[i][jj] = __builtin_amdgcn_mfma_f32_16x16x32_bf16(a[i], b[jj], acc[i][jj], 0, 0, 0);
            }
            __syncthreads();
        }

        // Epilogue A: scaled = (acc + b_cat) * uni -> bf16 -> Ss (swizzled [128][128])
        #pragma unroll
        for (int i = 0; i < 4; ++i) {
            int lm_base = wm * 64 + i * 16 + quad * 4;   // local row
            #pragma unroll
            for (int jj = 0; jj < 4; ++jj) {
                int col = wn * 64 + jj * 16 + l16;       // local col (the n-dim)
                float bv = bias[n0 + col];
                #pragma unroll
                for (int rr = 0; rr < 4; ++rr) {
                    int lm = lm_base + rr;
                    float v = (acc[i][jj][rr] + bv) * uni[(size_t)(m0 + lm) * POOL + n0 + col];
                    int ch = (col >> 3) ^ (lm & 15);
                    Ss[lm * 128 + ch * 8 + (col & 7)] = (bf16_t)v;
                }
            }
        }
        __syncthreads();

        // Epilogue B: acc2 += Ss(128x128) @ Wctx[n0:n0+128][0:64]
        #pragma unroll
        for (int kb = 0; kb < 4; ++kb) {   // K = 128, steps of 32
            bf16x8 a2[4], b2[2];
            #pragma unroll
            for (int i = 0; i < 4; ++i) {
                int m = wm * 64 + i * 16 + l16;
                int ch = (kb * 4 + quad) ^ (m & 15);
                a2[i] = *(const bf16x8*)&Ss[m * 128 + ch * 8];
            }
            #pragma unroll
            for (int jj = 0; jj < 2; ++jj) {
                int c = wn * 32 + jj * 16 + l16;   // class index 0..63
                b2[jj] = *(const bf16x8*)&Wctx_t[(size_t)c * POOL + n0 + kb * 32 + quad * 8];
            }
            #pragma unroll
            for (int i = 0; i < 4; ++i)
                #pragma unroll
                for (int jj = 0; jj < 2; ++jj)
                    acc2[i][jj] = __builtin_amdgcn_mfma_f32_16x16x32_bf16(a2[i], b2[jj], acc2[i][jj], 0, 0, 0);
        }
        __syncthreads();   // Ss reads done before next n-tile restages As/Bs (alias)
    }

    // Final: NB-way atomic add of the persistent partials.
    #pragma unroll
    for (int i = 0; i < 4; ++i) {
        int rbase = m0 + wm * 64 + i * 16 + quad * 4;
        #pragma unroll
        for (int jj = 0; jj < 2; ++jj) {
            int c = wn * 32 + jj * 16 + l16;
            if (c < NRC) {
                #pragma unroll
                for (int rr = 0; rr < 4; ++rr)
                    atomicAdd(&out[(size_t)(rbase + rr) * NRC + c], acc2[i][jj][rr]);
            }
        }
    }
}

// ---------------- launcher ----------------

extern "C" void kernel_launch(void* const* d_in, const int* in_sizes, int n_in,
                              void* d_out, int out_size, void* d_ws, size_t ws_size,
                              hipStream_t stream) {
    const float* edge_ctx = (const float*)d_in[0];
    const float* uni      = (const float*)d_in[1];
    const int*   rel      = (const int*)d_in[2];
    const int*   obj      = (const int*)d_in[3];
    const float* W_emb    = (const float*)d_in[4];
    const float* b_emb    = (const float*)d_in[5];
    const float* W_cat    = (const float*)d_in[6];
    const float* b_cat    = (const float*)d_in[7];
    const float* W_ctx    = (const float*)d_in[8];
    const float* b_ctx    = (const float*)d_in[9];
    const float* freq     = (const float*)d_in[10];
    float* out = (float*)d_out;

    char* p = (char*)d_ws;
    bf16_t* C1     = (bf16_t*)p; p += (size_t)N_OBJ * 1024 * 2;
    bf16_t* ecb    = (bf16_t*)p; p += (size_t)N_OBJ * HID * 2;
    bf16_t* Wemb_t = (bf16_t*)p; p += (size_t)1024 * HID * 2;
    bf16_t* Wcat_t = (bf16_t*)p; p += (size_t)POOL * 1024 * 2;
    bf16_t* Wctx_t = (bf16_t*)p; p += (size_t)64 * POOL * 2;

    convert_bf16_kernel<<<2048, 256, 0, stream>>>(edge_ctx, ecb, N_OBJ * HID / 4);
    transpose_bf16_kernel<<<dim3(1024 / 32, HID / 32), dim3(32, 8), 0, stream>>>(W_emb, Wemb_t, HID, 1024, 1024);
    transpose_bf16_kernel<<<dim3(POOL / 32, 1024 / 32), dim3(32, 8), 0, stream>>>(W_cat, Wcat_t, 1024, POOL, POOL);
    transpose_bf16_kernel<<<dim3(2, POOL / 32), dim3(32, 8), 0, stream>>>(W_ctx, Wctx_t, POOL, NRC, 64);
    init_out_kernel<<<N_REL / 4, 256, 0, stream>>>(rel, obj, b_ctx, freq, out);

    gemm1_kernel<<<dim3(N_OBJ / 128, 1024 / 128), 256, 0, stream>>>(ecb, Wemb_t, b_emb, C1);
    gemm2_fused_kernel<<<(N_REL / 128) * NB, 256, 0, stream>>>(C1, Wcat_t, Wctx_t, rel, b_cat, uni, out);
}

// Round 6
// 896.980 us; speedup vs baseline: 1.8984x; 1.5891x over previous
//
#include <hip/hip_runtime.h>
#include <hip/hip_bf16.h>

#define N_OBJ 8192
#define N_REL 32768
#define HID   512
#define POOL  4096
#define NOC   151
#define NRC   51

typedef __bf16 bf16_t;
typedef __attribute__((ext_vector_type(8))) __bf16 bf16x8;
typedef __attribute__((ext_vector_type(4))) __bf16 bf16x4;
typedef __attribute__((ext_vector_type(4))) float f32x4;

// Async global->LDS, 16B per lane. LDS dest semantics: wave-uniform base + lane*16.
__device__ __forceinline__ void async_copy16(const void* g, void* l) {
    __builtin_amdgcn_global_load_lds((__attribute__((address_space(1))) void*)g,
                                     (__attribute__((address_space(3))) void*)l,
                                     16, 0, 0);
}

// ---------------- small prep kernels ----------------

__global__ void convert_bf16_kernel(const float* __restrict__ in,
                                    bf16_t* __restrict__ out, int n4) {
    int i = blockIdx.x * blockDim.x + threadIdx.x;
    int stride = gridDim.x * blockDim.x;
    for (; i < n4; i += stride) {
        float4 v = ((const float4*)in)[i];
        bf16x4 o;
        o[0] = (bf16_t)v.x; o[1] = (bf16_t)v.y; o[2] = (bf16_t)v.z; o[3] = (bf16_t)v.w;
        ((bf16x4*)out)[i] = o;
    }
}

// in: f32 [K][C] row-major -> out: bf16 [Cpad][K] (transposed, zero-padded in C)
__global__ void transpose_bf16_kernel(const float* __restrict__ in,
                                      bf16_t* __restrict__ out,
                                      int K, int C, int Cpad) {
    __shared__ float tile[32][33];
    int cb = blockIdx.x * 32, kb = blockIdx.y * 32;
    int tx = threadIdx.x, ty = threadIdx.y; // 32 x 8
    #pragma unroll
    for (int i = 0; i < 32; i += 8) {
        int k = kb + ty + i, c = cb + tx;
        float v = (k < K && c < C) ? in[(size_t)k * C + c] : 0.0f;
        tile[ty + i][tx] = v;
    }
    __syncthreads();
    #pragma unroll
    for (int i = 0; i < 32; i += 8) {
        int c = cb + ty + i, k = kb + tx;
        if (c < Cpad && k < K) out[(size_t)c * K + k] = (bf16_t)tile[tx][ty + i];
    }
}

// ---------------- GEMM1: C1 = relu(ec @ Wemb + b), bf16 out [8192][1024] ----------------
// (unchanged, known-good)

__global__ __launch_bounds__(256, 2) void gemm1_kernel(
    const bf16_t* __restrict__ A,    // [8192][512]
    const bf16_t* __restrict__ Bt,   // [1024][512]
    const float* __restrict__ bias,  // [1024]
    bf16_t* __restrict__ C)          // [8192][1024]
{
    __shared__ __align__(16) bf16_t As[128 * 64];
    __shared__ __align__(16) bf16_t Bs[128 * 64];
    const int tid = threadIdx.x;
    const int w = tid >> 6, lane = tid & 63;
    const int m0 = blockIdx.x * 128, n0 = blockIdx.y * 128;
    const int lrow = tid >> 3, lcs = tid & 7;
    const int wm = w & 1, wn = w >> 1;
    const int quad = lane >> 4, l16 = lane & 15;
    f32x4 acc[4][4] = {};

    for (int kt = 0; kt < HID / 64; ++kt) {
        const int k0 = kt * 64;
        #pragma unroll
        for (int j = 0; j < 4; ++j) {
            int ml = j * 32 + lrow;
            int cg = lcs ^ (ml & 7);
            async_copy16(A + (size_t)(m0 + ml) * HID + k0 + cg * 8, &As[ml * 64 + lcs * 8]);
        }
        #pragma unroll
        for (int j = 0; j < 4; ++j) {
            int nl = j * 32 + lrow;
            int cg = lcs ^ (nl & 7);
            async_copy16(Bt + (size_t)(n0 + nl) * HID + k0 + cg * 8, &Bs[nl * 64 + lcs * 8]);
        }
        __syncthreads();
        #pragma unroll
        for (int kb = 0; kb < 2; ++kb) {
            bf16x8 a[4], b[4];
            #pragma unroll
            for (int i = 0; i < 4; ++i) {
                int m = wm * 64 + i * 16 + l16;
                int ch = (kb * 4 + quad) ^ (m & 7);
                a[i] = *(const bf16x8*)&As[m * 64 + ch * 8];
            }
            #pragma unroll
            for (int i = 0; i < 4; ++i) {
                int n = wn * 64 + i * 16 + l16;
                int ch = (kb * 4 + quad) ^ (n & 7);
                b[i] = *(const bf16x8*)&Bs[n * 64 + ch * 8];
            }
            #pragma unroll
            for (int i = 0; i < 4; ++i)
                #pragma unroll
                for (int jj = 0; jj < 4; ++jj)
                    acc[i][jj] = __builtin_amdgcn_mfma_f32_16x16x32_bf16(a[i], b[jj], acc[i][jj], 0, 0, 0);
        }
        __syncthreads();
    }
    #pragma unroll
    for (int i = 0; i < 4; ++i) {
        int rbase = m0 + wm * 64 + i * 16 + quad * 4;
        #pragma unroll
        for (int jj = 0; jj < 4; ++jj) {
            int c = n0 + wn * 64 + jj * 16 + l16;
            float bv = bias[c];
            #pragma unroll
            for (int rr = 0; rr < 4; ++rr) {
                float v = acc[i][jj][rr] + bv;
                v = fmaxf(v, 0.0f);
                C[(size_t)(rbase + rr) * 1024 + c] = (bf16_t)v;
            }
        }
    }
}

// ---------------- GEMM1b: HW = C1[:, 0:512] @ Wcat[0:512, :],  TW = C1[:,512:] @ Wcat[512:,:] ----
// Same proven 128x128/BK=64 structure as gemm1. blockIdx.z selects the half.
// Key algebraic move: prod_rep[r] = HW[i0[r]] + TW[i1[r]] + b_cat  (per-OBJECT GEMM,
// 68.7 GF total instead of the 274.9 GF per-RELATION GEMM).

__global__ __launch_bounds__(256, 2) void gemm_half_kernel(
    const bf16_t* __restrict__ C1,     // [8192][1024]
    const bf16_t* __restrict__ Wcat_t, // [4096][1024]
    bf16_t* __restrict__ HWb,          // [8192][4096]
    bf16_t* __restrict__ TWb)          // [8192][4096]
{
    __shared__ __align__(16) bf16_t As[128 * 64];
    __shared__ __align__(16) bf16_t Bs[128 * 64];
    const int tid = threadIdx.x;
    const int w = tid >> 6, lane = tid & 63;
    const int m0 = blockIdx.x * 128, n0 = blockIdx.y * 128;
    const int koff = blockIdx.z * 512;
    bf16_t* const Cout = blockIdx.z ? TWb : HWb;
    const int lrow = tid >> 3, lcs = tid & 7;
    const int wm = w & 1, wn = w >> 1;
    const int quad = lane >> 4, l16 = lane & 15;
    f32x4 acc[4][4] = {};

    for (int kt = 0; kt < 8; ++kt) {   // K = 512
        const int k0 = koff + kt * 64;
        #pragma unroll
        for (int j = 0; j < 4; ++j) {
            int ml = j * 32 + lrow;
            int cg = lcs ^ (ml & 7);
            async_copy16(C1 + (size_t)(m0 + ml) * 1024 + k0 + cg * 8, &As[ml * 64 + lcs * 8]);
        }
        #pragma unroll
        for (int j = 0; j < 4; ++j) {
            int nl = j * 32 + lrow;
            int cg = lcs ^ (nl & 7);
            async_copy16(Wcat_t + (size_t)(n0 + nl) * 1024 + k0 + cg * 8, &Bs[nl * 64 + lcs * 8]);
        }
        __syncthreads();
        #pragma unroll
        for (int kb = 0; kb < 2; ++kb) {
            bf16x8 a[4], b[4];
            #pragma unroll
            for (int i = 0; i < 4; ++i) {
                int m = wm * 64 + i * 16 + l16;
                int ch = (kb * 4 + quad) ^ (m & 7);
                a[i] = *(const bf16x8*)&As[m * 64 + ch * 8];
            }
            #pragma unroll
            for (int i = 0; i < 4; ++i) {
                int n = wn * 64 + i * 16 + l16;
                int ch = (kb * 4 + quad) ^ (n & 7);
                b[i] = *(const bf16x8*)&Bs[n * 64 + ch * 8];
            }
            #pragma unroll
            for (int i = 0; i < 4; ++i)
                #pragma unroll
                for (int jj = 0; jj < 4; ++jj)
                    acc[i][jj] = __builtin_amdgcn_mfma_f32_16x16x32_bf16(a[i], b[jj], acc[i][jj], 0, 0, 0);
        }
        __syncthreads();
    }
    #pragma unroll
    for (int i = 0; i < 4; ++i) {
        int rbase = m0 + wm * 64 + i * 16 + quad * 4;
        #pragma unroll
        for (int jj = 0; jj < 4; ++jj) {
            int c = n0 + wn * 64 + jj * 16 + l16;
            #pragma unroll
            for (int rr = 0; rr < 4; ++rr)
                Cout[(size_t)(rbase + rr) * POOL + c] = (bf16_t)acc[i][jj][rr];
        }
    }
}

// ---------------- rel_fused: out = ((HW[i0]+TW[i1]+b_cat)*uni) @ Wctx + b_ctx + freq ----------------
// Streaming, occupancy-first: 512 blocks x 512 threads (8 waves), 64-row tile,
// 32 KB LDS (double-buffered Ss [64][128] bf16), ~8-reg accumulator.
// One barrier per K-chunk: scale-pass(kc+1) overlaps MFMA(kc) (T3-minimum shape).
// out written exactly once (freq/b_ctx fused) -> no atomics, no init kernel.

__global__ __launch_bounds__(512, 2) void rel_fused_kernel(
    const bf16_t* __restrict__ HWb,    // [8192][4096]
    const bf16_t* __restrict__ TWb,    // [8192][4096]
    const bf16_t* __restrict__ Wctx_t, // [64][4096] (rows 51..63 zero)
    const int* __restrict__ rel,       // [32768][2]
    const int* __restrict__ obj,       // [8192]
    const float* __restrict__ b_cat,   // [4096]
    const float* __restrict__ b_ctx,   // [51]
    const float* __restrict__ freq,    // [NOC*NOC][51]
    const float* __restrict__ uni,     // [32768][4096]
    float* __restrict__ out)           // [32768][51]
{
    __shared__ __align__(16) bf16_t Ss[2][64 * 128];
    const int tid = threadIdx.x;
    const int w = tid >> 6, lane = tid & 63;
    const int quad = lane >> 4, l16 = lane & 15;
    const int wm = w & 1, wn = w >> 1;        // 2 row-halves x 4 class-groups
    const int lr = tid >> 3, hc = tid & 7;    // 64 rows x 8 col-groups (16 cols each)
    const int m0 = blockIdx.x * 64;

    const int myrow = m0 + lr;
    const int gi0 = rel[2 * myrow], gi1 = rel[2 * myrow + 1];
    const bf16_t* hwrow = HWb + (size_t)gi0 * POOL;
    const bf16_t* twrow = TWb + (size_t)gi1 * POOL;
    const float*  urow  = uni + (size_t)myrow * POOL;

    f32x4 acc2[2] = {};

    auto scale_pass = [&](int kc, bf16_t* S) {
        const int cbase = kc * 128 + hc * 16;
        #pragma unroll
        for (int cg = 0; cg < 2; ++cg) {
            const int cc = cbase + cg * 8;
            bf16x8 hw = *(const bf16x8*)&hwrow[cc];
            bf16x8 tw = *(const bf16x8*)&twrow[cc];
            float4 u0 = *(const float4*)&urow[cc];
            float4 u1 = *(const float4*)&urow[cc + 4];
            float4 b0 = *(const float4*)&b_cat[cc];
            float4 b1 = *(const float4*)&b_cat[cc + 4];
            bf16x8 s;
            s[0] = (bf16_t)(((float)hw[0] + (float)tw[0] + b0.x) * u0.x);
            s[1] = (bf16_t)(((float)hw[1] + (float)tw[1] + b0.y) * u0.y);
            s[2] = (bf16_t)(((float)hw[2] + (float)tw[2] + b0.z) * u0.z);
            s[3] = (bf16_t)(((float)hw[3] + (float)tw[3] + b0.w) * u0.w);
            s[4] = (bf16_t)(((float)hw[4] + (float)tw[4] + b1.x) * u1.x);
            s[5] = (bf16_t)(((float)hw[5] + (float)tw[5] + b1.y) * u1.y);
            s[6] = (bf16_t)(((float)hw[6] + (float)tw[6] + b1.z) * u1.z);
            s[7] = (bf16_t)(((float)hw[7] + (float)tw[7] + b1.w) * u1.w);
            const int colc = hc * 2 + cg;      // 16-byte chunk index 0..15
            *(bf16x8*)&S[lr * 128 + ((colc ^ (lr & 15)) << 3)] = s;
        }
    };
    auto mma_pass = [&](int kc, const bf16_t* S) {
        #pragma unroll
        for (int kb = 0; kb < 4; ++kb) {       // K = 128 per chunk
            bf16x8 a2[2], b2;
            #pragma unroll
            for (int i = 0; i < 2; ++i) {
                int m = wm * 32 + i * 16 + l16;
                a2[i] = *(const bf16x8*)&S[m * 128 + (((kb * 4 + quad) ^ (m & 15)) << 3)];
            }
            int c = wn * 16 + l16;             // class index 0..63
            b2 = *(const bf16x8*)&Wctx_t[(size_t)c * POOL + kc * 128 + kb * 32 + quad * 8];
            #pragma unroll
            for (int i = 0; i < 2; ++i)
                acc2[i] = __builtin_amdgcn_mfma_f32_16x16x32_bf16(a2[i], b2, acc2[i], 0, 0, 0);
        }
    };

    scale_pass(0, Ss[0]);
    __syncthreads();
    for (int kc = 0; kc < 32; ++kc) {
        bf16_t* Scur = Ss[kc & 1];
        bf16_t* Snxt = Ss[(kc & 1) ^ 1];
        if (kc < 31) scale_pass(kc + 1, Snxt);   // overlaps with mma of current chunk
        mma_pass(kc, Scur);
        __syncthreads();
    }

    // Epilogue: fold b_ctx + freq gather, single store per output element.
    #pragma unroll
    for (int i = 0; i < 2; ++i) {
        #pragma unroll
        for (int rr = 0; rr < 4; ++rr) {
            int row = m0 + wm * 32 + i * 16 + quad * 4 + rr;
            int c = wn * 16 + l16;
            if (c < NRC) {
                int pid = obj[rel[2 * row]] * NOC + obj[rel[2 * row + 1]];
                out[(size_t)row * NRC + c] =
                    acc2[i][rr] + b_ctx[c] + freq[(size_t)pid * NRC + c];
            }
        }
    }
}

// ---------------- launcher ----------------

extern "C" void kernel_launch(void* const* d_in, const int* in_sizes, int n_in,
                              void* d_out, int out_size, void* d_ws, size_t ws_size,
                              hipStream_t stream) {
    const float* edge_ctx = (const float*)d_in[0];
    const float* uni      = (const float*)d_in[1];
    const int*   rel      = (const int*)d_in[2];
    const int*   obj      = (const int*)d_in[3];
    const float* W_emb    = (const float*)d_in[4];
    const float* b_emb    = (const float*)d_in[5];
    const float* W_cat    = (const float*)d_in[6];
    const float* b_cat    = (const float*)d_in[7];
    const float* W_ctx    = (const float*)d_in[8];
    const float* b_ctx    = (const float*)d_in[9];
    const float* freq     = (const float*)d_in[10];
    float* out = (float*)d_out;

    char* p = (char*)d_ws;
    bf16_t* C1     = (bf16_t*)p; p += (size_t)N_OBJ * 1024 * 2;   // 16 MB
    bf16_t* ecb    = (bf16_t*)p; p += (size_t)N_OBJ * HID * 2;    //  8 MB
    bf16_t* Wemb_t = (bf16_t*)p; p += (size_t)1024 * HID * 2;     //  1 MB
    bf16_t* Wcat_t = (bf16_t*)p; p += (size_t)POOL * 1024 * 2;    //  8 MB
    bf16_t* Wctx_t = (bf16_t*)p; p += (size_t)64 * POOL * 2;      //  0.5 MB
    bf16_t* HWb    = (bf16_t*)p; p += (size_t)N_OBJ * POOL * 2;   // 64 MB
    bf16_t* TWb    = (bf16_t*)p; p += (size_t)N_OBJ * POOL * 2;   // 64 MB

    convert_bf16_kernel<<<2048, 256, 0, stream>>>(edge_ctx, ecb, N_OBJ * HID / 4);
    transpose_bf16_kernel<<<dim3(1024 / 32, HID / 32), dim3(32, 8), 0, stream>>>(W_emb, Wemb_t, HID, 1024, 1024);
    transpose_bf16_kernel<<<dim3(POOL / 32, 1024 / 32), dim3(32, 8), 0, stream>>>(W_cat, Wcat_t, 1024, POOL, POOL);
    transpose_bf16_kernel<<<dim3(2, POOL / 32), dim3(32, 8), 0, stream>>>(W_ctx, Wctx_t, POOL, NRC, 64);

    gemm1_kernel<<<dim3(N_OBJ / 128, 1024 / 128), 256, 0, stream>>>(ecb, Wemb_t, b_emb, C1);
    gemm_half_kernel<<<dim3(N_OBJ / 128, POOL / 128, 2), 256, 0, stream>>>(C1, Wcat_t, HWb, TWb);
    rel_fused_kernel<<<N_REL / 64, 512, 0, stream>>>(HWb, TWb, Wctx_t, rel, obj,
                                                     b_cat, b_ctx, freq, uni, out);
}